// Round 4
// baseline (218.839 us; speedup 1.0000x reference)
//
#include <hip/hip_runtime.h>
#include <math.h>

// DSHW (double-seasonal Holt-Winters) — R4: vm-traffic-free scan loop.
// R3 post-mortem: the scan was stalled ~90% (VALUBusy 9.4% on active CUs);
// 3 vm ops/iter (strided y load + 2 strided f32 stores) paced the loop via
// in-order vmcnt retirement. R4 moves y to a transposed ws buffer (float4
// loads, 1 per 4 steps, 8-step prefetch), stores yhat as f64 double2 into a
// transposed ws buffer (2 per 4 steps), and defers yhat_f32/e/fcast/Ic/wc
// output to a parallel finish kernel. Every f64 expression is textually
// identical to the R2/R3 passing kernels -> bit-identical outputs.

#define P1c   24
#define P2c   168
#define NSTEP 512
#define BSc   64
#define NFc   16
#define MAXH  336
#define NT    32
#define NSERIES 1024

#define OFF_FC   0
#define OFF_YH   (BSc * MAXH * NFc)
#define OFF_E    (OFF_YH + BSc * NSTEP * NFc)
#define OFF_IC   (OFF_E  + BSc * NSTEP * NFc)
#define OFF_WC   (OFF_IC + BSc * P1c * NFc)
#define OFF_T    (OFF_WC + BSc * P2c * NFc)
#define OFF_S    (OFF_T  + BSc * NFc)

// ws layout (bytes)
#define WSO_Y    0                                    // f32 [NSERIES][NSTEP]
#define WSO_YH   (WSO_Y + (size_t)NSERIES*NSTEP*4)    // f64 [NSERIES][NSTEP]
#define WSO_ST   (WSO_YH + (size_t)NSERIES*NSTEP*8)   // f64 [194][NSERIES]
#define WS_NEED_FULL (WSO_ST + (size_t)194*NSERIES*8)

// ---------------------------------------------------------------------------
// Kernel A: transpose y [64][512][16] f32 -> ws_y [1024][512] f32
// ---------------------------------------------------------------------------
__global__ __launch_bounds__(256)
void dshw_transpose_y(const float* __restrict__ y, float* __restrict__ wsy)
{
    __shared__ float tile[16][17];
    const int b   = blockIdx.x;
    const int tid = threadIdx.x;
    const float* __restrict__ yb = y + (size_t)b * NSTEP * NFc;
    float* __restrict__ wb = wsy + (size_t)b * NFc * NSTEP;
    const int r  = tid >> 4, c  = tid & 15;   // load mapping
    const int f  = tid >> 4, nI = tid & 15;   // store mapping
    for (int n0 = 0; n0 < NSTEP; n0 += 16) {
        tile[r][c] = yb[(n0 + r) * NFc + c];          // coalesced 1 KB
        __syncthreads();
        wb[f * NSTEP + n0 + nI] = tile[nI][f];        // coalesced 64B runs
        __syncthreads();
    }
}

// ---------------------------------------------------------------------------
// Kernel B: init + pipelined 512-step scan. yhat -> ws (f64), state -> ws.
// ---------------------------------------------------------------------------
__global__ __launch_bounds__(NT, 1)
void dshw_scan2(const float* __restrict__ wsy,
                const float* __restrict__ alphas,
                const float* __restrict__ betas,
                const float* __restrict__ gammas,
                const float* __restrict__ omegas,
                double* __restrict__ wsyh,
                double* __restrict__ wsst,
                float* __restrict__ out)
{
    __shared__ double sIc[P1c][NT];
    __shared__ double sWc[P2c][NT];

    const int tid = threadIdx.x;
    const int g   = blockIdx.x * NT + tid;
    const int bb  = g >> 4;
    const int f   = g & 15;

    const float* __restrict__ yr = wsy + (size_t)g * NSTEP;

    const double al = 1.0 / (1.0 + exp(-(double)alphas[f]));
    const double be = 1.0 / (1.0 + exp(-(double)betas[f]));
    const double ga = 1.0 / (1.0 + exp(-(double)gammas[f]));
    const double om = 1.0 / (1.0 + exp(-(double)omegas[f]));

    // ---------------- init (expressions identical to R2/R3) ----------------
    double sum48 = 0.0;
    #pragma unroll
    for (int ph = 0; ph < P1c; ++ph) {
        double v0 = (double)yr[ph];
        double v1 = (double)yr[ph + P1c];
        sIc[ph][tid] = 0.5 * (v0 + v1);
        sum48 += v0 + v1;
    }
    const double inv_mean48 = 48.0 / sum48;
    #pragma unroll
    for (int ph = 0; ph < P1c; ++ph) sIc[ph][tid] *= inv_mean48;

    double sum168a = 0.0, sum168b = 0.0;
    #pragma unroll 8
    for (int i = 0; i < P2c; ++i) {
        double v0 = (double)yr[i];
        double v1 = (double)yr[i + P2c];
        sWc[i][tid] = 0.5 * (v0 + v1);
        sum168a += v0;
        sum168b += v1;
    }
    const double mean336 = (sum168a + sum168b) * (1.0 / 336.0);
    #pragma unroll 8
    for (int i = 0; i < P2c; ++i) {
        sWc[i][tid] = (sWc[i][tid] / mean336) / sIc[i % P1c][tid];
    }

    double tt = 0.5 * ((sum168a - sum168b) * (1.0 / (168.0 * 168.0)) +
                       ((double)yr[P2c - 1] - (double)yr[0]) * (1.0 / 168.0));
    double ss = mean336 - 168.5 * tt;

    // ---------------- pipelined scan ----------------
    // stages at iter s: A reads state for step s+6; B computes step s+2
    // (divide #1); C = the chain for step s; D finishes step s-2 (divide #2).
    const float4* __restrict__ yr4 = (const float4*)yr;
    double* __restrict__ yhb = wsyh + (size_t)g * NSTEP;

    double ytd[12];   // y(sg-4+k)
    {
        float4 a0 = yr4[0], a1 = yr4[1], a2 = yr4[2];
        ytd[0]=(double)a0.x; ytd[1]=(double)a0.y; ytd[2]=(double)a0.z; ytd[3]=(double)a0.w;
        ytd[4]=(double)a1.x; ytd[5]=(double)a1.y; ytd[6]=(double)a1.z; ytd[7]=(double)a1.w;
        ytd[8]=(double)a2.x; ytd[9]=(double)a2.y; ytd[10]=(double)a2.z; ytd[11]=(double)a2.w;
    }
    float4 fq0 = yr4[3];   // y(12..15)
    float4 fq1 = yr4[4];   // y(16..19)

    // warmup: steps 0..3 (C), B for steps 0..5, D for steps 0..1
    double Iw[10], Ww[10];
    #pragma unroll
    for (int p = 0; p < 10; ++p) { Iw[p] = sIc[p][tid]; Ww[p] = sWc[p][tid]; }

    double iwB[6], uB[6], pIB[6], pWB[6];
    #pragma unroll
    for (int m = 0; m < 6; ++m) {
        double iw  = Iw[m] * Ww[m];
        double inv = 1.0 / iw;
        iwB[m] = iw;
        uB[m]  = ytd[m] * inv;
        pIB[m] = inv * Iw[m];
        pWB[m] = inv * Ww[m];
    }
    double snw[4], yhw[4];
    #pragma unroll
    for (int m = 0; m < 4; ++m) {
        double spt  = ss + tt;
        double yhat = spt * iwB[m];
        double snew = al * uB[m] + (1.0 - al) * spt;
        double tnew = be * (snew - ss) + (1.0 - be) * tt;
        yhw[m] = yhat; snw[m] = snew;
        ss = snew; tt = tnew;
    }
    { double2 v; v.x = yhw[0]; v.y = yhw[1]; *(double2*)(yhb + 0) = v; }
    { double2 v; v.x = yhw[2]; v.y = yhw[3]; *(double2*)(yhb + 2) = v; }
    #pragma unroll
    for (int m = 0; m < 2; ++m) {
        double q   = ytd[m] / snw[m];
        double icn = ga * (q * pIB[m]) + (1.0 - ga) * Iw[m];
        double wcn = om * (q * pWB[m]) + (1.0 - om) * Ww[m];
        sIc[m][tid] = icn;
        sWc[m][tid] = wcn;
    }

    // queues (invariants at group start sg):
    double Icq[12], wcq[12];  // Ic(sg-2+k), k=0..7 occupied
    double iwq[6],  uq[6];    // iw(sg+k), k=0..1
    double pIq[8],  pWq[8];   // pI(sg-2+k), k=0..3
    double snq[6];            // snew(sg-2+k), k=0..1
    #pragma unroll
    for (int k = 0; k < 8; ++k) { Icq[k] = Iw[2 + k]; wcq[k] = Ww[2 + k]; }
    iwq[0] = iwB[4]; iwq[1] = iwB[5];
    uq[0]  = uB[4];  uq[1]  = uB[5];
    #pragma unroll
    for (int k = 0; k < 4; ++k) { pIq[k] = pIB[2 + k]; pWq[k] = pWB[2 + k]; }
    snq[0] = snw[2]; snq[1] = snw[3];

    int i1r = 10, i2r = 10;   // phase of step sg+j+6 at sg=4, j=0
    int i1w = 2,  i2w = 2;    // phase of step sg+j-2 at sg=4, j=0

    for (int sg = 4; sg <= 504; sg += 4) {
        double yhv[4];
        #pragma unroll
        for (int j = 0; j < 4; ++j) {
            // A: read state for step sg+j+6
            Icq[8 + j] = sIc[i1r][tid];
            wcq[8 + j] = sWc[i2r][tid];
            i1r = (i1r + 1 == P1c) ? 0 : i1r + 1;
            i2r = (i2r + 1 == P2c) ? 0 : i2r + 1;
            // B: step sg+j+2 (divide #1, off-chain)
            double iw2  = Icq[j + 4] * wcq[j + 4];
            double inv2 = 1.0 / iw2;
            iwq[j + 2] = iw2;
            uq[j + 2]  = ytd[j + 6] * inv2;
            pIq[j + 4] = inv2 * Icq[j + 4];
            pWq[j + 4] = inv2 * wcq[j + 4];
            // C: step sg+j (the chain)
            double spt  = ss + tt;
            double yhat = spt * iwq[j];
            double snew = al * uq[j] + (1.0 - al) * spt;
            double tnew = be * (snew - ss) + (1.0 - be) * tt;
            snq[j + 2] = snew;
            yhv[j] = yhat;
            ss = snew; tt = tnew;
            // D: step sg+j-2 (divide #2, off-chain)
            double q   = ytd[j + 2] / snq[j];
            double icn = ga * (q * pIq[j]) + (1.0 - ga) * Icq[j];
            double wcn = om * (q * pWq[j]) + (1.0 - om) * wcq[j];
            sIc[i1w][tid] = icn;
            sWc[i2w][tid] = wcn;
            i1w = (i1w + 1 == P1c) ? 0 : i1w + 1;
            i2w = (i2w + 1 == P2c) ? 0 : i2w + 1;
        }
        // yhat out (per-thread contiguous, 16B)
        { double2 v; v.x = yhv[0]; v.y = yhv[1]; *(double2*)(yhb + sg)     = v; }
        { double2 v; v.x = yhv[2]; v.y = yhv[3]; *(double2*)(yhb + sg + 2) = v; }
        // y queue advance (float4 fetched 2 groups ahead)
        #pragma unroll
        for (int k = 0; k < 8; ++k) ytd[k] = ytd[k + 4];
        ytd[8]  = (double)fq0.x; ytd[9]  = (double)fq0.y;
        ytd[10] = (double)fq0.z; ytd[11] = (double)fq0.w;
        fq0 = fq1;
        int nb = sg + 16; nb = (nb > 508) ? 508 : nb;
        fq1 = *(const float4*)(yr + nb);
        // queue shifts
        #pragma unroll
        for (int k = 0; k < 8; ++k) { Icq[k] = Icq[k + 4]; wcq[k] = wcq[k + 4]; }
        iwq[0] = iwq[4]; iwq[1] = iwq[5];
        uq[0]  = uq[4];  uq[1]  = uq[5];
        #pragma unroll
        for (int k = 0; k < 4; ++k) { pIq[k] = pIq[k + 4]; pWq[k] = pWq[k + 4]; }
        snq[0] = snq[4]; snq[1] = snq[5];
    }

    // tail: steps 508..511 (C), B for 510..511, D for 506..511
    {
        double iwA  = Icq[4] * wcq[4];  double invA = 1.0 / iwA;
        double uA   = ytd[6] * invA;
        double pIA  = invA * Icq[4];    double pWA  = invA * wcq[4];
        double iwBt = Icq[5] * wcq[5];  double invB = 1.0 / iwBt;
        double uBt  = ytd[7] * invB;
        double pIBt = invB * Icq[5];    double pWBt = invB * wcq[5];

        double sn[4], yh[4];
        double iws[4] = { iwq[0], iwq[1], iwA, iwBt };
        double us[4]  = { uq[0],  uq[1],  uA,  uBt  };
        #pragma unroll
        for (int m = 0; m < 4; ++m) {
            double spt  = ss + tt;
            double yhat = spt * iws[m];
            double snew = al * us[m] + (1.0 - al) * spt;
            double tnew = be * (snew - ss) + (1.0 - be) * tt;
            yh[m] = yhat; sn[m] = snew;
            ss = snew; tt = tnew;
        }
        { double2 v; v.x = yh[0]; v.y = yh[1]; *(double2*)(yhb + 508) = v; }
        { double2 v; v.x = yh[2]; v.y = yh[3]; *(double2*)(yhb + 510) = v; }

        double snD[6] = { snq[0], snq[1], sn[0], sn[1], sn[2], sn[3] };
        double pID[6] = { pIq[0], pIq[1], pIq[2], pIq[3], pIA, pIBt };
        double pWD[6] = { pWq[0], pWq[1], pWq[2], pWq[3], pWA, pWBt };
        #pragma unroll
        for (int m = 0; m < 6; ++m) {
            double q   = ytd[m + 2] / snD[m];
            double icn = ga * (q * pID[m]) + (1.0 - ga) * Icq[m];
            double wcn = om * (q * pWD[m]) + (1.0 - om) * wcq[m];
            sIc[i1w][tid] = icn;
            sWc[i2w][tid] = wcn;
            i1w = (i1w + 1 == P1c) ? 0 : i1w + 1;
            i2w = (i2w + 1 == P2c) ? 0 : i2w + 1;
        }
    }

    // dump raw f64 state, item-major
    #pragma unroll 8
    for (int p = 0; p < P1c; ++p)  wsst[(size_t)p * NSERIES + g] = sIc[p][tid];
    #pragma unroll 8
    for (int p = 0; p < P2c; ++p)  wsst[(size_t)(P1c + p) * NSERIES + g] = sWc[p][tid];
    wsst[(size_t)192 * NSERIES + g] = ss;
    wsst[(size_t)193 * NSERIES + g] = tt;

    out[OFF_T + bb * NFc + f] = (float)tt;
    out[OFF_S + bb * NFc + f] = (float)ss;
}

// ---------------------------------------------------------------------------
// Kernel C: finish — yhat f32, e, fcast, rolled Ic/wc. 1040 items x 64 b x 16 f.
// ---------------------------------------------------------------------------
__global__ __launch_bounds__(256)
void dshw_finish(const float* __restrict__ y,
                 const double* __restrict__ wsyh,
                 const double* __restrict__ wsst,
                 float* __restrict__ out)
{
    const int f      = threadIdx.x & 15;
    const int isub   = threadIdx.x >> 4;
    const int bb     = blockIdx.x & 63;
    const int chunk  = blockIdx.x >> 6;       // 0..64
    const int item   = chunk * 16 + isub;     // 0..1039
    const int series = bb * NFc + f;

    if (item < NSTEP) {
        const int n = item;
        double yh = wsyh[(size_t)series * NSTEP + n];
        double yt = (double)y[((size_t)bb * NSTEP + n) * NFc + f];
        out[OFF_YH + (bb * NSTEP + n) * NFc + f] = (float)yh;
        out[OFF_E  + (bb * NSTEP + n) * NFc + f] = (float)(yt - yh);
    } else if (item < NSTEP + MAXH) {
        const int k = item - NSTEP;
        double cb = wsst[(size_t)((k + 8) % P1c) * NSERIES + series];
        double cc = wsst[(size_t)(P1c + (k + 8) % P2c) * NSERIES + series];
        double ssv = wsst[(size_t)192 * NSERIES + series];
        double ttv = wsst[(size_t)193 * NSERIES + series];
        double ca = ssv + (double)(k + 1) * ttv;
        out[OFF_FC + (bb * MAXH + k) * NFc + f] = (float)(ca * cb * cc);
    } else if (item < NSTEP + MAXH + P1c) {
        const int j = item - (NSTEP + MAXH);
        out[OFF_IC + (bb * P1c + j) * NFc + f] =
            (float)wsst[(size_t)((j + 8) % P1c) * NSERIES + series];
    } else if (item < NSTEP + MAXH + P1c + P2c) {
        const int j = item - (NSTEP + MAXH + P1c);
        out[OFF_WC + (bb * P2c + j) * NFc + f] =
            (float)wsst[(size_t)(P1c + (j + 8) % P2c) * NSERIES + series];
    }
}

// ---------------------------------------------------------------------------
// Fallback (R2 fused kernel, verbatim) — used only if ws is too small.
// ---------------------------------------------------------------------------
__global__ __launch_bounds__(NT, 1)
void dshw_fused(const float* __restrict__ y,
                const float* __restrict__ alphas,
                const float* __restrict__ betas,
                const float* __restrict__ gammas,
                const float* __restrict__ omegas,
                float* __restrict__ out)
{
    __shared__ double sIc[P1c][NT];
    __shared__ double sWc[P2c][NT];

    const int tid = threadIdx.x;
    const int g   = blockIdx.x * NT + tid;
    const int bb  = g >> 4;
    const int f   = g & 15;

    const float* __restrict__ yb = y + (size_t)bb * NSTEP * NFc + f;

    const double al = 1.0 / (1.0 + exp(-(double)alphas[f]));
    const double be = 1.0 / (1.0 + exp(-(double)betas[f]));
    const double ga = 1.0 / (1.0 + exp(-(double)gammas[f]));
    const double om = 1.0 / (1.0 + exp(-(double)omegas[f]));

    double sum48 = 0.0;
    #pragma unroll
    for (int ph = 0; ph < P1c; ++ph) {
        double v0 = (double)yb[ph * NFc];
        double v1 = (double)yb[(ph + P1c) * NFc];
        sIc[ph][tid] = 0.5 * (v0 + v1);
        sum48 += v0 + v1;
    }
    const double inv_mean48 = 48.0 / sum48;
    #pragma unroll
    for (int ph = 0; ph < P1c; ++ph) sIc[ph][tid] *= inv_mean48;

    double sum168a = 0.0, sum168b = 0.0;
    for (int i = 0; i < P2c; ++i) {
        double v0 = (double)yb[i * NFc];
        double v1 = (double)yb[(i + P2c) * NFc];
        sWc[i][tid] = 0.5 * (v0 + v1);
        sum168a += v0;
        sum168b += v1;
    }
    const double mean336 = (sum168a + sum168b) * (1.0 / 336.0);
    for (int i = 0; i < P2c; ++i) {
        sWc[i][tid] = (sWc[i][tid] / mean336) / sIc[i % P1c][tid];
    }

    double tt = 0.5 * ((sum168a - sum168b) * (1.0 / (168.0 * 168.0)) +
                       ((double)yb[(P2c - 1) * NFc] - (double)yb[0]) * (1.0 / 168.0));
    double ss = mean336 - 168.5 * tt;

    float* __restrict__ yh_o = out + OFF_YH + (size_t)bb * NSTEP * NFc + f;
    float* __restrict__ e_o  = out + OFF_E  + (size_t)bb * NSTEP * NFc + f;

    int i1 = 0, i2 = 0;
    int i1p = 2, i2p = 2;

    double Icv0 = sIc[0][tid], Icv1 = sIc[1][tid];
    double wcv0 = sWc[0][tid], wcv1 = sWc[1][tid];
    double yt0 = (double)yb[0 * NFc], yt1 = (double)yb[1 * NFc];
    double yt2 = (double)yb[2 * NFc], yt3 = (double)yb[3 * NFc];

    #pragma unroll 4
    for (int step = 0; step < NSTEP; ++step) {
        double Icv2 = sIc[i1p][tid];
        double wcv2 = sWc[i2p][tid];
        int    pidx = step + 4; pidx = (pidx < NSTEP) ? pidx : (NSTEP - 1);
        double yt4  = (double)yb[pidx * NFc];

        double iw     = Icv0 * wcv0;
        double spt    = ss + tt;
        double yhat   = spt * iw;
        double inv_iw = 1.0 / iw;
        double u      = yt0 * inv_iw;
        double snew   = al * u + (1.0 - al) * spt;
        double tnew   = be * (snew - ss) + (1.0 - be) * tt;
        double q      = yt0 / snew;
        double icn    = ga * (q * (inv_iw * Icv0)) + (1.0 - ga) * Icv0;
        double wcn    = om * (q * (inv_iw * wcv0)) + (1.0 - om) * wcv0;

        sIc[i1][tid] = icn;
        sWc[i2][tid] = wcn;
        yh_o[step * NFc] = (float)yhat;
        e_o[step * NFc]  = (float)(yt0 - yhat);

        ss = snew; tt = tnew;
        Icv0 = Icv1; Icv1 = Icv2;
        wcv0 = wcv1; wcv1 = wcv2;
        yt0 = yt1; yt1 = yt2; yt2 = yt3; yt3 = yt4;
        i1  = (i1  + 1 == P1c) ? 0 : i1  + 1;
        i2  = (i2  + 1 == P2c) ? 0 : i2  + 1;
        i1p = (i1p + 1 == P1c) ? 0 : i1p + 1;
        i2p = (i2p + 1 == P2c) ? 0 : i2p + 1;
    }

    float* __restrict__ fc_o = out + OFF_FC + (size_t)bb * MAXH * NFc + f;
    {
        int k1 = 8, k2 = 8;
        for (int k = 0; k < MAXH; ++k) {
            double cb = sIc[k1][tid];
            double cc = sWc[k2][tid];
            double ca = ss + (double)(k + 1) * tt;
            fc_o[k * NFc] = (float)(ca * cb * cc);
            k1 = (k1 + 1 == P1c) ? 0 : k1 + 1;
            k2 = (k2 + 1 == P2c) ? 0 : k2 + 1;
        }
    }
    {
        float* __restrict__ ic_o = out + OFF_IC + (size_t)bb * P1c * NFc + f;
        int k1 = 8;
        #pragma unroll
        for (int j = 0; j < P1c; ++j) {
            ic_o[j * NFc] = (float)sIc[k1][tid];
            k1 = (k1 + 1 == P1c) ? 0 : k1 + 1;
        }
    }
    {
        float* __restrict__ wc_o = out + OFF_WC + (size_t)bb * P2c * NFc + f;
        int k2 = 8;
        for (int j = 0; j < P2c; ++j) {
            wc_o[j * NFc] = (float)sWc[k2][tid];
            k2 = (k2 + 1 == P2c) ? 0 : k2 + 1;
        }
    }

    out[OFF_T + bb * NFc + f] = (float)tt;
    out[OFF_S + bb * NFc + f] = (float)ss;
}

extern "C" void kernel_launch(void* const* d_in, const int* in_sizes, int n_in,
                              void* d_out, int out_size, void* d_ws, size_t ws_size,
                              hipStream_t stream)
{
    const float* y      = (const float*)d_in[0];
    const float* alphas = (const float*)d_in[1];
    const float* betas  = (const float*)d_in[2];
    const float* gammas = (const float*)d_in[3];
    const float* omegas = (const float*)d_in[4];
    float* out = (float*)d_out;

    if (ws_size >= WS_NEED_FULL) {
        float*  wsy  = (float*)((char*)d_ws + WSO_Y);
        double* wsyh = (double*)((char*)d_ws + WSO_YH);
        double* wsst = (double*)((char*)d_ws + WSO_ST);
        hipLaunchKernelGGL(dshw_transpose_y, dim3(BSc), dim3(256), 0, stream, y, wsy);
        hipLaunchKernelGGL(dshw_scan2, dim3(NSERIES / NT), dim3(NT), 0, stream,
                           wsy, alphas, betas, gammas, omegas, wsyh, wsst, out);
        hipLaunchKernelGGL(dshw_finish, dim3(65 * BSc), dim3(256), 0, stream,
                           y, wsyh, wsst, out);
    } else {
        hipLaunchKernelGGL(dshw_fused, dim3(NSERIES / NT), dim3(NT), 0, stream,
                           y, alphas, betas, gammas, omegas, out);
    }
}

// Round 5
// 186.354 us; speedup vs baseline: 1.1743x; 1.1743x over previous
//
#include <hip/hip_runtime.h>
#include <math.h>

// DSHW — R5: VCC-free f64 reciprocals.
// R4 post-mortem: IEEE f64 divides serialize on VCC (v_div_scale writes VCC,
// v_div_fmas reads it) -> 8 divides/group cannot interleave; their ~250-cycle
// dependent chains serialize = the observed 90% stall. R5 replaces all hot
// divides with v_rcp_f64 + 2 Newton FMAs (no VCC, ~1 ulp, schedulable).
// Numerics: absmax margin is the reference's own f32 noise; our ~1e-16/step
// perturbations amplify to ~1e-10 relative — invisible.

#define P1c   24
#define P2c   168
#define NSTEP 512
#define BSc   64
#define NFc   16
#define MAXH  336
#define NT    32
#define NSERIES 1024

#define OFF_FC   0
#define OFF_YH   (BSc * MAXH * NFc)
#define OFF_E    (OFF_YH + BSc * NSTEP * NFc)
#define OFF_IC   (OFF_E  + BSc * NSTEP * NFc)
#define OFF_WC   (OFF_IC + BSc * P1c * NFc)
#define OFF_T    (OFF_WC + BSc * P2c * NFc)
#define OFF_S    (OFF_T  + BSc * NFc)

#define WS_NEED ((size_t)194 * NSERIES * sizeof(double))

__device__ __forceinline__ double nrcp(double a) {
    double x = __builtin_amdgcn_rcp(a);          // v_rcp_f64, no VCC
    x = fma(fma(-a, x, 1.0), x, x);
    x = fma(fma(-a, x, 1.0), x, x);              // ~1 ulp
    return x;
}

// ---------------------------------------------------------------------------
// Kernel 1: init + pipelined 512-step scan (divide-free inner loop).
// ---------------------------------------------------------------------------
__global__ __launch_bounds__(NT, 1)
void dshw_scan3(const float* __restrict__ y,
                const float* __restrict__ alphas,
                const float* __restrict__ betas,
                const float* __restrict__ gammas,
                const float* __restrict__ omegas,
                double* __restrict__ wsst,
                float* __restrict__ out)
{
    __shared__ double sIc[P1c][NT];
    __shared__ double sWc[P2c][NT];

    const int tid = threadIdx.x;
    const int g   = blockIdx.x * NT + tid;
    const int bb  = g >> 4;
    const int f   = g & 15;

    const float* __restrict__ yb = y + (size_t)bb * NSTEP * NFc + f;

    const double al = 1.0 / (1.0 + exp(-(double)alphas[f]));
    const double be = 1.0 / (1.0 + exp(-(double)betas[f]));
    const double ga = 1.0 / (1.0 + exp(-(double)gammas[f]));
    const double om = 1.0 / (1.0 + exp(-(double)omegas[f]));
    const double one_m_al = 1.0 - al, one_m_be = 1.0 - be;
    const double one_m_ga = 1.0 - ga, one_m_om = 1.0 - om;

    // ---------------- init ----------------
    double sum48 = 0.0;
    #pragma unroll
    for (int ph = 0; ph < P1c; ++ph) {
        double v0 = (double)yb[ph * NFc];
        double v1 = (double)yb[(ph + P1c) * NFc];
        sIc[ph][tid] = 0.5 * (v0 + v1);
        sum48 += v0 + v1;
    }
    const double inv_mean48 = 48.0 * nrcp(sum48);
    #pragma unroll
    for (int ph = 0; ph < P1c; ++ph) sIc[ph][tid] *= inv_mean48;

    double sum168a = 0.0, sum168b = 0.0;
    #pragma unroll 8
    for (int i = 0; i < P2c; ++i) {
        double v0 = (double)yb[i * NFc];
        double v1 = (double)yb[(i + P2c) * NFc];
        sWc[i][tid] = 0.5 * (v0 + v1);
        sum168a += v0;
        sum168b += v1;
    }
    const double mean336     = (sum168a + sum168b) * (1.0 / 336.0);
    const double inv_mean336 = nrcp(mean336);
    #pragma unroll 8
    for (int i = 0; i < P2c; ++i) {
        // (sWc/mean336)/sIc — as mults by VCC-free reciprocals (interleavable)
        sWc[i][tid] = (sWc[i][tid] * inv_mean336) * nrcp(sIc[i % P1c][tid]);
    }

    double tt = 0.5 * ((sum168a - sum168b) * (1.0 / (168.0 * 168.0)) +
                       ((double)yb[(P2c - 1) * NFc] - (double)yb[0]) * (1.0 / 168.0));
    double ss = mean336 - 168.5 * tt;

    // ---------------- pipelined scan ----------------
    // stage schedule at iter s: A reads state for s+6; B computes iw,u for
    // s+2 (recip #1); C = the chain at s; D finishes s-2 (recip #2).
    float* __restrict__ yh_o = out + OFF_YH + (size_t)bb * NSTEP * NFc + f;
    float* __restrict__ e_o  = out + OFF_E  + (size_t)bb * NSTEP * NFc + f;

    double yw[16];
    #pragma unroll
    for (int k = 0; k < 16; ++k) yw[k] = (double)yb[k * NFc];

    double Iw[10], Ww[10];
    #pragma unroll
    for (int p = 0; p < 10; ++p) { Iw[p] = sIc[p][tid]; Ww[p] = sWc[p][tid]; }

    // B warmup for steps 0..5
    double iwB[6], uB[6];
    #pragma unroll
    for (int m = 0; m < 6; ++m) {
        double iw  = Iw[m] * Ww[m];
        double inv = nrcp(iw);
        iwB[m] = iw;
        uB[m]  = yw[m] * inv;
    }
    // C warmup for steps 0..3
    double snw[4];
    #pragma unroll
    for (int m = 0; m < 4; ++m) {
        double spt  = ss + tt;
        double yhat = spt * iwB[m];
        double snew = al * uB[m] + one_m_al * spt;
        double tnew = be * (snew - ss) + one_m_be * tt;
        yh_o[m * NFc] = (float)yhat;
        e_o[m * NFc]  = (float)(yw[m] - yhat);
        snw[m] = snew;
        ss = snew; tt = tnew;
    }
    // D warmup for steps 0..1
    #pragma unroll
    for (int m = 0; m < 2; ++m) {
        double r   = nrcp(snw[m]);
        double icn = ga * ((uB[m] * Iw[m]) * r) + one_m_ga * Iw[m];
        double wcn = om * ((uB[m] * Ww[m]) * r) + one_m_om * Ww[m];
        sIc[m][tid] = icn;
        sWc[m][tid] = wcn;
    }

    // queues (invariants at group start sg):
    double ytd[16];           // ytd[k] = y_{sg-2+k}, k=0..13 live
    #pragma unroll
    for (int k = 0; k < 14; ++k) ytd[k] = yw[k + 2];
    double Icq[12], wcq[12];  // Icq[k] = Ic_{sg-2+k} (pre-update), k=0..7 live
    #pragma unroll
    for (int k = 0; k < 8; ++k) { Icq[k] = Iw[2 + k]; wcq[k] = Ww[2 + k]; }
    double iwq[6], uq[6];     // iwq[k]=iw_{sg+k}, uq[k]=u_{sg+k}, k=0..1 live
    iwq[0] = iwB[4]; iwq[1] = iwB[5];
    uq[0]  = uB[4];  uq[1]  = uB[5];
    double uD0 = uB[2], uD1 = uB[3];   // u_{sg-2}, u_{sg-1}
    double snq[6];            // snq[k] = snew_{sg-2+k}, k=0..1 live
    snq[0] = snw[2]; snq[1] = snw[3];

    int i1r = 10, i2r = 10;   // phase of step sg+j+6 at sg=4, j=0
    int i1w = 2,  i2w = 2;    // phase of step sg+j-2 at sg=4, j=0

    for (int sg = 4; sg <= 504; sg += 4) {
        #pragma unroll
        for (int j = 0; j < 4; ++j) {
            // A: state for step sg+j+6
            Icq[8 + j] = sIc[i1r][tid];
            wcq[8 + j] = sWc[i2r][tid];
            i1r = (i1r + 1 == P1c) ? 0 : i1r + 1;
            i2r = (i2r + 1 == P2c) ? 0 : i2r + 1;
            // y prefetch: y_{sg+j+10}
            int pidx = sg + j + 10; pidx = (pidx < NSTEP) ? pidx : (NSTEP - 1);
            ytd[12 + j] = (double)yb[pidx * NFc];
            // B: step sg+j+2 (recip #1, off-chain, VCC-free)
            double iw2  = Icq[j + 4] * wcq[j + 4];
            double inv2 = nrcp(iw2);
            iwq[j + 2] = iw2;
            uq[j + 2]  = ytd[j + 4] * inv2;
            // C: step sg+j (the chain)
            double spt  = ss + tt;
            double yhat = spt * iwq[j];
            double snew = al * uq[j] + one_m_al * spt;
            double tnew = be * (snew - ss) + one_m_be * tt;
            yh_o[(sg + j) * NFc] = (float)yhat;
            e_o[(sg + j) * NFc]  = (float)(ytd[j + 2] - yhat);
            snq[j + 2] = snew;
            ss = snew; tt = tnew;
            // D: step sg+j-2 (recip #2, off-chain, VCC-free)
            double uD  = (j == 0) ? uD0 : (j == 1) ? uD1 : uq[j - 2];
            double r   = nrcp(snq[j]);
            double icn = ga * ((uD * Icq[j]) * r) + one_m_ga * Icq[j];
            double wcn = om * ((uD * wcq[j]) * r) + one_m_om * wcq[j];
            sIc[i1w][tid] = icn;
            sWc[i2w][tid] = wcn;
            i1w = (i1w + 1 == P1c) ? 0 : i1w + 1;
            i2w = (i2w + 1 == P2c) ? 0 : i2w + 1;
        }
        // shifts (uD before uq!)
        uD0 = uq[2]; uD1 = uq[3];
        uq[0] = uq[4];  uq[1] = uq[5];
        iwq[0] = iwq[4]; iwq[1] = iwq[5];
        snq[0] = snq[4]; snq[1] = snq[5];
        #pragma unroll
        for (int k = 0; k < 12; ++k) ytd[k] = ytd[k + 4];
        #pragma unroll
        for (int k = 0; k < 8; ++k) { Icq[k] = Icq[k + 4]; wcq[k] = wcq[k + 4]; }
    }

    // tail: sg=508. C for 508..511, B for 510..511, D for 506..511.
    {
        double iwA = Icq[4] * wcq[4];  double uA = ytd[4] * nrcp(iwA);
        double iwB2 = Icq[5] * wcq[5]; double uB2 = ytd[5] * nrcp(iwB2);

        double iws[4] = { iwq[0], iwq[1], iwA, iwB2 };
        double us[4]  = { uq[0],  uq[1],  uA,  uB2  };
        double sn[4];
        #pragma unroll
        for (int m = 0; m < 4; ++m) {
            double spt  = ss + tt;
            double yhat = spt * iws[m];
            double snew = al * us[m] + one_m_al * spt;
            double tnew = be * (snew - ss) + one_m_be * tt;
            yh_o[(508 + m) * NFc] = (float)yhat;
            e_o[(508 + m) * NFc]  = (float)(ytd[2 + m] - yhat);
            sn[m] = snew;
            ss = snew; tt = tnew;
        }
        double snD[6] = { snq[0], snq[1], sn[0], sn[1], sn[2], sn[3] };
        double uDt[6] = { uD0, uD1, uq[0], uq[1], uA, uB2 };
        #pragma unroll
        for (int m = 0; m < 6; ++m) {
            double r   = nrcp(snD[m]);
            double icn = ga * ((uDt[m] * Icq[m]) * r) + one_m_ga * Icq[m];
            double wcn = om * ((uDt[m] * wcq[m]) * r) + one_m_om * wcq[m];
            sIc[i1w][tid] = icn;
            sWc[i2w][tid] = wcn;
            i1w = (i1w + 1 == P1c) ? 0 : i1w + 1;
            i2w = (i2w + 1 == P2c) ? 0 : i2w + 1;
        }
    }

    // dump raw f64 state, item-major (lanes -> consecutive series)
    #pragma unroll 8
    for (int p = 0; p < P1c; ++p)  wsst[(size_t)p * NSERIES + g] = sIc[p][tid];
    #pragma unroll 8
    for (int p = 0; p < P2c; ++p)  wsst[(size_t)(P1c + p) * NSERIES + g] = sWc[p][tid];
    wsst[(size_t)192 * NSERIES + g] = ss;
    wsst[(size_t)193 * NSERIES + g] = tt;

    out[OFF_T + bb * NFc + f] = (float)tt;
    out[OFF_S + bb * NFc + f] = (float)ss;
}

// ---------------------------------------------------------------------------
// Kernel 2: parallel epilogue — fcast + rolled Ic/wc from f64 ws state.
// 528 items: 0..335 fcast k, 336..359 Ic j, 360..527 wc j.
// ---------------------------------------------------------------------------
__global__ __launch_bounds__(256)
void dshw_epilogue(const double* __restrict__ ws, float* __restrict__ out)
{
    const int f      = threadIdx.x & 15;
    const int isub   = threadIdx.x >> 4;
    const int bb     = blockIdx.x & 63;
    const int chunk  = blockIdx.x >> 6;
    const int item   = chunk * 16 + isub;
    const int series = bb * NFc + f;

    if (item < MAXH) {
        const int k = item;
        double cb = ws[(size_t)((k + 8) % P1c) * NSERIES + series];
        double cc = ws[(size_t)(P1c + (k + 8) % P2c) * NSERIES + series];
        double ss = ws[(size_t)192 * NSERIES + series];
        double tt = ws[(size_t)193 * NSERIES + series];
        double ca = ss + (double)(k + 1) * tt;
        out[OFF_FC + (bb * MAXH + k) * NFc + f] = (float)(ca * cb * cc);
    } else if (item < MAXH + P1c) {
        const int j = item - MAXH;
        out[OFF_IC + (bb * P1c + j) * NFc + f] =
            (float)ws[(size_t)((j + 8) % P1c) * NSERIES + series];
    } else if (item < MAXH + P1c + P2c) {
        const int j = item - (MAXH + P1c);
        out[OFF_WC + (bb * P2c + j) * NFc + f] =
            (float)ws[(size_t)(P1c + (j + 8) % P2c) * NSERIES + series];
    }
}

// ---------------------------------------------------------------------------
// Fallback (R2 fused kernel, verbatim) — used only if ws is too small.
// ---------------------------------------------------------------------------
__global__ __launch_bounds__(NT, 1)
void dshw_fused(const float* __restrict__ y,
                const float* __restrict__ alphas,
                const float* __restrict__ betas,
                const float* __restrict__ gammas,
                const float* __restrict__ omegas,
                float* __restrict__ out)
{
    __shared__ double sIc[P1c][NT];
    __shared__ double sWc[P2c][NT];

    const int tid = threadIdx.x;
    const int g   = blockIdx.x * NT + tid;
    const int bb  = g >> 4;
    const int f   = g & 15;

    const float* __restrict__ yb = y + (size_t)bb * NSTEP * NFc + f;

    const double al = 1.0 / (1.0 + exp(-(double)alphas[f]));
    const double be = 1.0 / (1.0 + exp(-(double)betas[f]));
    const double ga = 1.0 / (1.0 + exp(-(double)gammas[f]));
    const double om = 1.0 / (1.0 + exp(-(double)omegas[f]));

    double sum48 = 0.0;
    #pragma unroll
    for (int ph = 0; ph < P1c; ++ph) {
        double v0 = (double)yb[ph * NFc];
        double v1 = (double)yb[(ph + P1c) * NFc];
        sIc[ph][tid] = 0.5 * (v0 + v1);
        sum48 += v0 + v1;
    }
    const double inv_mean48 = 48.0 / sum48;
    #pragma unroll
    for (int ph = 0; ph < P1c; ++ph) sIc[ph][tid] *= inv_mean48;

    double sum168a = 0.0, sum168b = 0.0;
    for (int i = 0; i < P2c; ++i) {
        double v0 = (double)yb[i * NFc];
        double v1 = (double)yb[(i + P2c) * NFc];
        sWc[i][tid] = 0.5 * (v0 + v1);
        sum168a += v0;
        sum168b += v1;
    }
    const double mean336 = (sum168a + sum168b) * (1.0 / 336.0);
    for (int i = 0; i < P2c; ++i) {
        sWc[i][tid] = (sWc[i][tid] / mean336) / sIc[i % P1c][tid];
    }

    double tt = 0.5 * ((sum168a - sum168b) * (1.0 / (168.0 * 168.0)) +
                       ((double)yb[(P2c - 1) * NFc] - (double)yb[0]) * (1.0 / 168.0));
    double ss = mean336 - 168.5 * tt;

    float* __restrict__ yh_o = out + OFF_YH + (size_t)bb * NSTEP * NFc + f;
    float* __restrict__ e_o  = out + OFF_E  + (size_t)bb * NSTEP * NFc + f;

    int i1 = 0, i2 = 0;
    int i1p = 2, i2p = 2;

    double Icv0 = sIc[0][tid], Icv1 = sIc[1][tid];
    double wcv0 = sWc[0][tid], wcv1 = sWc[1][tid];
    double yt0 = (double)yb[0 * NFc], yt1 = (double)yb[1 * NFc];
    double yt2 = (double)yb[2 * NFc], yt3 = (double)yb[3 * NFc];

    #pragma unroll 4
    for (int step = 0; step < NSTEP; ++step) {
        double Icv2 = sIc[i1p][tid];
        double wcv2 = sWc[i2p][tid];
        int    pidx = step + 4; pidx = (pidx < NSTEP) ? pidx : (NSTEP - 1);
        double yt4  = (double)yb[pidx * NFc];

        double iw     = Icv0 * wcv0;
        double spt    = ss + tt;
        double yhat   = spt * iw;
        double inv_iw = 1.0 / iw;
        double u      = yt0 * inv_iw;
        double snew   = al * u + (1.0 - al) * spt;
        double tnew   = be * (snew - ss) + (1.0 - be) * tt;
        double q      = yt0 / snew;
        double icn    = ga * (q * (inv_iw * Icv0)) + (1.0 - ga) * Icv0;
        double wcn    = om * (q * (inv_iw * wcv0)) + (1.0 - om) * wcv0;

        sIc[i1][tid] = icn;
        sWc[i2][tid] = wcn;
        yh_o[step * NFc] = (float)yhat;
        e_o[step * NFc]  = (float)(yt0 - yhat);

        ss = snew; tt = tnew;
        Icv0 = Icv1; Icv1 = Icv2;
        wcv0 = wcv1; wcv1 = wcv2;
        yt0 = yt1; yt1 = yt2; yt2 = yt3; yt3 = yt4;
        i1  = (i1  + 1 == P1c) ? 0 : i1  + 1;
        i2  = (i2  + 1 == P2c) ? 0 : i2  + 1;
        i1p = (i1p + 1 == P1c) ? 0 : i1p + 1;
        i2p = (i2p + 1 == P2c) ? 0 : i2p + 1;
    }

    float* __restrict__ fc_o = out + OFF_FC + (size_t)bb * MAXH * NFc + f;
    {
        int k1 = 8, k2 = 8;
        for (int k = 0; k < MAXH; ++k) {
            double cb = sIc[k1][tid];
            double cc = sWc[k2][tid];
            double ca = ss + (double)(k + 1) * tt;
            fc_o[k * NFc] = (float)(ca * cb * cc);
            k1 = (k1 + 1 == P1c) ? 0 : k1 + 1;
            k2 = (k2 + 1 == P2c) ? 0 : k2 + 1;
        }
    }
    {
        float* __restrict__ ic_o = out + OFF_IC + (size_t)bb * P1c * NFc + f;
        int k1 = 8;
        #pragma unroll
        for (int j = 0; j < P1c; ++j) {
            ic_o[j * NFc] = (float)sIc[k1][tid];
            k1 = (k1 + 1 == P1c) ? 0 : k1 + 1;
        }
    }
    {
        float* __restrict__ wc_o = out + OFF_WC + (size_t)bb * P2c * NFc + f;
        int k2 = 8;
        for (int j = 0; j < P2c; ++j) {
            wc_o[j * NFc] = (float)sWc[k2][tid];
            k2 = (k2 + 1 == P2c) ? 0 : k2 + 1;
        }
    }

    out[OFF_T + bb * NFc + f] = (float)tt;
    out[OFF_S + bb * NFc + f] = (float)ss;
}

extern "C" void kernel_launch(void* const* d_in, const int* in_sizes, int n_in,
                              void* d_out, int out_size, void* d_ws, size_t ws_size,
                              hipStream_t stream)
{
    const float* y      = (const float*)d_in[0];
    const float* alphas = (const float*)d_in[1];
    const float* betas  = (const float*)d_in[2];
    const float* gammas = (const float*)d_in[3];
    const float* omegas = (const float*)d_in[4];
    float* out = (float*)d_out;

    if (ws_size >= WS_NEED) {
        double* wsst = (double*)d_ws;
        hipLaunchKernelGGL(dshw_scan3, dim3(NSERIES / NT), dim3(NT), 0, stream,
                           y, alphas, betas, gammas, omegas, wsst, out);
        hipLaunchKernelGGL(dshw_epilogue, dim3(33 * BSc), dim3(256), 0, stream,
                           wsst, out);
    } else {
        hipLaunchKernelGGL(dshw_fused, dim3(NSERIES / NT), dim3(NT), 0, stream,
                           y, alphas, betas, gammas, omegas, out);
    }
}

// Round 6
// 147.270 us; speedup vs baseline: 1.4860x; 1.2654x over previous
//
#include <hip/hip_runtime.h>
#include <math.h>

// DSHW — R6: fully-unrolled 24-step groups, Ic in registers, ring buffers
// with compile-time indices (no queue-shift v_movs), 1 LDS read + 1 LDS
// write per step, shared u*r in the D-stage. f64 throughout (the recursion
// amplifies perturbations ~e^16+; f64 noise stays ~1e-10 relative, invisible
// under the harness threshold which is set by the reference's own f32 noise).
//
// Pipeline at iteration j of a 24-group starting at s0 (s = s0 + j):
//   C: the serial chain for step s (reads iwring, uring, yring)
//   A: LDS-read wc phase (s+12), global-load y_{s+12}
//   B: off-chain recip #1 for step s+4 (iw, u)
//   D: off-chain recip #2 for step s-2 (Ic register update, wc LDS write)
// Ring slot of value m is m % R with R | 24 -> indices fold after unroll.

#define P1c   24
#define P2c   168
#define NSTEP 512
#define BSc   64
#define NFc   16
#define MAXH  336
#define NT    32
#define NSERIES 1024

#define OFF_FC   0
#define OFF_YH   (BSc * MAXH * NFc)
#define OFF_E    (OFF_YH + BSc * NSTEP * NFc)
#define OFF_IC   (OFF_E  + BSc * NSTEP * NFc)
#define OFF_WC   (OFF_IC + BSc * P1c * NFc)
#define OFF_T    (OFF_WC + BSc * P2c * NFc)
#define OFF_S    (OFF_T  + BSc * NFc)

#define WS_NEED ((size_t)194 * NSERIES * sizeof(double))

__device__ __forceinline__ double nrcp(double a) {
    double x = __builtin_amdgcn_rcp(a);          // v_rcp_f64, no VCC
    x = fma(fma(-a, x, 1.0), x, x);
    x = fma(fma(-a, x, 1.0), x, x);              // ~1 ulp
    return x;
}

__global__ __launch_bounds__(NT, 1)
void dshw_scan4(const float* __restrict__ y,
                const float* __restrict__ alphas,
                const float* __restrict__ betas,
                const float* __restrict__ gammas,
                const float* __restrict__ omegas,
                double* __restrict__ wsst,
                float* __restrict__ out)
{
    __shared__ double sW[P2c][NT];   // wc only — 42 KiB

    const int tid = threadIdx.x;
    const int g   = blockIdx.x * NT + tid;
    const int bb  = g >> 4;
    const int f   = g & 15;

    const float* __restrict__ yb = y + (size_t)bb * NSTEP * NFc + f;

    const double al = 1.0 / (1.0 + exp(-(double)alphas[f]));
    const double be = 1.0 / (1.0 + exp(-(double)betas[f]));
    const double ga = 1.0 / (1.0 + exp(-(double)gammas[f]));
    const double om = 1.0 / (1.0 + exp(-(double)omegas[f]));
    const double one_m_al = 1.0 - al, one_m_be = 1.0 - be;
    const double one_m_ga = 1.0 - ga, one_m_om = 1.0 - om;

    // ---------------- init ----------------
    double Icr[P1c];
    double sum48 = 0.0;
    #pragma unroll
    for (int ph = 0; ph < P1c; ++ph) {
        double v0 = (double)yb[ph * NFc];
        double v1 = (double)yb[(ph + P1c) * NFc];
        Icr[ph] = 0.5 * (v0 + v1);
        sum48 += v0 + v1;
    }
    const double inv_mean48 = 48.0 * nrcp(sum48);
    #pragma unroll
    for (int ph = 0; ph < P1c; ++ph) Icr[ph] *= inv_mean48;

    double sa = 0.0, sb = 0.0;
    #pragma unroll 8
    for (int i = 0; i < P2c; ++i) {
        double v0 = (double)yb[i * NFc];
        double v1 = (double)yb[(i + P2c) * NFc];
        sW[i][tid] = 0.5 * (v0 + v1);
        sa += v0; sb += v1;
    }
    const double mean336     = (sa + sb) * (1.0 / 336.0);
    const double inv_mean336 = nrcp(mean336);
    #pragma unroll
    for (int ph = 0; ph < P1c; ++ph) {
        double rI = inv_mean336 * nrcp(Icr[ph]);   // 24 recips instead of 168
        #pragma unroll
        for (int r = 0; r < 7; ++r) {
            const int i = ph + 24 * r;
            sW[i][tid] = sW[i][tid] * rI;
        }
    }

    double tt = 0.5 * ((sa - sb) * (1.0 / (168.0 * 168.0)) +
                       ((double)yb[(P2c - 1) * NFc] - (double)yb[0]) * (1.0 / 168.0));
    double ss = mean336 - 168.5 * tt;

    // ---------------- scan ----------------
    float* __restrict__ yh_o = out + OFF_YH + (size_t)bb * NSTEP * NFc + f;
    float* __restrict__ e_o  = out + OFF_E  + (size_t)bb * NSTEP * NFc + f;

    double yring[12], wring[24], uring[8], iwring[6], snring[3];

    #pragma unroll
    for (int k = 0; k < 12; ++k) yring[k] = (double)yb[k * NFc];
    #pragma unroll
    for (int k = 0; k < 12; ++k) wring[k] = sW[k][tid];
    // B warmup: steps 0..3
    #pragma unroll
    for (int m = 0; m < 4; ++m) {
        double iw  = Icr[m] * wring[m];
        double inv = nrcp(iw);
        iwring[m % 6] = iw;
        uring[m % 8]  = yring[m % 12] * inv;
    }

    int i2r = 12;   // LDS read phase (s+12) % 168
    int i2w = 0;    // LDS write phase (s-2) % 168

    // ---- group 0 (s0 = 0): D guarded for j < 2 ----
    #pragma unroll
    for (int j = 0; j < 24; ++j) {
        const int s = j;
        // C
        double yv   = yring[j % 12];
        double spt  = ss + tt;
        double yhat = spt * iwring[j % 6];
        double snew = al * uring[j % 8] + one_m_al * spt;
        double tnew = be * (snew - ss) + one_m_be * tt;
        yh_o[s * NFc] = (float)yhat;
        e_o[s * NFc]  = (float)(yv - yhat);
        snring[j % 3] = snew;
        ss = snew; tt = tnew;
        // A
        wring[(j + 12) % 24] = sW[i2r][tid];
        i2r = (i2r + 1 == P2c) ? 0 : i2r + 1;
        yring[j % 12] = (double)yb[(s + 12) * NFc];
        // B (step s+4)
        {
            double iw2  = Icr[(j + 4) % 24] * wring[(j + 4) % 24];
            double inv2 = nrcp(iw2);
            iwring[(j + 4) % 6] = iw2;
            uring[(j + 4) % 8]  = yring[(j + 4) % 12] * inv2;
        }
        // D (step s-2)
        if (j >= 2) {
            double r   = nrcp(snring[(j + 1) % 3]);
            double uDr = uring[(j + 6) % 8] * r;
            double icO = Icr[(j + 22) % 24];
            double wcO = wring[(j + 22) % 24];
            Icr[(j + 22) % 24] = icO * fma(ga, uDr, one_m_ga);
            sW[i2w][tid] = wcO * fma(om, uDr, one_m_om);
            i2w = (i2w + 1 == P2c) ? 0 : i2w + 1;
        }
    }

    // ---- steady groups: s0 = 24..480 ----
    for (int s0 = 24; s0 <= 480; s0 += 24) {
        #pragma unroll
        for (int j = 0; j < 24; ++j) {
            const int s = s0 + j;
            // C
            double yv   = yring[j % 12];
            double spt  = ss + tt;
            double yhat = spt * iwring[j % 6];
            double snew = al * uring[j % 8] + one_m_al * spt;
            double tnew = be * (snew - ss) + one_m_be * tt;
            yh_o[s * NFc] = (float)yhat;
            e_o[s * NFc]  = (float)(yv - yhat);
            snring[j % 3] = snew;
            ss = snew; tt = tnew;
            // A
            wring[(j + 12) % 24] = sW[i2r][tid];
            i2r = (i2r + 1 == P2c) ? 0 : i2r + 1;
            int pidx = s + 12; pidx = (pidx < NSTEP) ? pidx : (NSTEP - 1);
            yring[j % 12] = (double)yb[pidx * NFc];
            // B (step s+4)
            {
                double iw2  = Icr[(j + 4) % 24] * wring[(j + 4) % 24];
                double inv2 = nrcp(iw2);
                iwring[(j + 4) % 6] = iw2;
                uring[(j + 4) % 8]  = yring[(j + 4) % 12] * inv2;
            }
            // D (step s-2)
            {
                double r   = nrcp(snring[(j + 1) % 3]);
                double uDr = uring[(j + 6) % 8] * r;
                double icO = Icr[(j + 22) % 24];
                double wcO = wring[(j + 22) % 24];
                Icr[(j + 22) % 24] = icO * fma(ga, uDr, one_m_ga);
                sW[i2w][tid] = wcO * fma(om, uDr, one_m_om);
                i2w = (i2w + 1 == P2c) ? 0 : i2w + 1;
            }
        }
    }

    // ---- tail: steps 504..511 (s0 = 504, 504 % 24 == 0, 504 % 168 == 0) ----
    #pragma unroll
    for (int j = 0; j < 8; ++j) {
        const int s = 504 + j;
        double yv   = yring[j % 12];
        double spt  = ss + tt;
        double yhat = spt * iwring[j % 6];
        double snew = al * uring[j % 8] + one_m_al * spt;
        double tnew = be * (snew - ss) + one_m_be * tt;
        yh_o[s * NFc] = (float)yhat;
        e_o[s * NFc]  = (float)(yv - yhat);
        snring[j % 3] = snew;
        ss = snew; tt = tnew;
        if (j < 4) {   // B for steps 508..511
            double iw2  = Icr[(j + 4) % 24] * wring[(j + 4) % 24];
            double inv2 = nrcp(iw2);
            iwring[(j + 4) % 6] = iw2;
            uring[(j + 4) % 8]  = yring[(j + 4) % 12] * inv2;
        }
        {   // D for steps 502..509
            double r   = nrcp(snring[(j + 1) % 3]);
            double uDr = uring[(j + 6) % 8] * r;
            double icO = Icr[(j + 22) % 24];
            double wcO = wring[(j + 22) % 24];
            Icr[(j + 22) % 24] = icO * fma(ga, uDr, one_m_ga);
            sW[i2w][tid] = wcO * fma(om, uDr, one_m_om);
            i2w = (i2w + 1 == P2c) ? 0 : i2w + 1;
        }
    }
    // drain D: step 510 (j=8), step 511 (j=9)
    {
        double r   = nrcp(snring[0]);
        double uDr = uring[6] * r;
        double icO = Icr[6], wcO = wring[6];
        Icr[6] = icO * fma(ga, uDr, one_m_ga);
        sW[i2w][tid] = wcO * fma(om, uDr, one_m_om);
        i2w = (i2w + 1 == P2c) ? 0 : i2w + 1;
    }
    {
        double r   = nrcp(snring[1]);
        double uDr = uring[7] * r;
        double icO = Icr[7], wcO = wring[7];
        Icr[7] = icO * fma(ga, uDr, one_m_ga);
        sW[i2w][tid] = wcO * fma(om, uDr, one_m_om);
    }

    // dump raw f64 state, item-major (lanes -> consecutive series)
    #pragma unroll
    for (int p = 0; p < P1c; ++p)  wsst[(size_t)p * NSERIES + g] = Icr[p];
    #pragma unroll 8
    for (int p = 0; p < P2c; ++p)  wsst[(size_t)(P1c + p) * NSERIES + g] = sW[p][tid];
    wsst[(size_t)192 * NSERIES + g] = ss;
    wsst[(size_t)193 * NSERIES + g] = tt;

    out[OFF_T + bb * NFc + f] = (float)tt;
    out[OFF_S + bb * NFc + f] = (float)ss;
}

// ---------------------------------------------------------------------------
// Kernel 2: parallel epilogue — fcast + rolled Ic/wc from f64 ws state.
// ---------------------------------------------------------------------------
__global__ __launch_bounds__(256)
void dshw_epilogue(const double* __restrict__ ws, float* __restrict__ out)
{
    const int f      = threadIdx.x & 15;
    const int isub   = threadIdx.x >> 4;
    const int bb     = blockIdx.x & 63;
    const int chunk  = blockIdx.x >> 6;
    const int item   = chunk * 16 + isub;
    const int series = bb * NFc + f;

    if (item < MAXH) {
        const int k = item;
        double cb = ws[(size_t)((k + 8) % P1c) * NSERIES + series];
        double cc = ws[(size_t)(P1c + (k + 8) % P2c) * NSERIES + series];
        double ss = ws[(size_t)192 * NSERIES + series];
        double tt = ws[(size_t)193 * NSERIES + series];
        double ca = ss + (double)(k + 1) * tt;
        out[OFF_FC + (bb * MAXH + k) * NFc + f] = (float)(ca * cb * cc);
    } else if (item < MAXH + P1c) {
        const int j = item - MAXH;
        out[OFF_IC + (bb * P1c + j) * NFc + f] =
            (float)ws[(size_t)((j + 8) % P1c) * NSERIES + series];
    } else if (item < MAXH + P1c + P2c) {
        const int j = item - (MAXH + P1c);
        out[OFF_WC + (bb * P2c + j) * NFc + f] =
            (float)ws[(size_t)(P1c + (j + 8) % P2c) * NSERIES + series];
    }
}

// ---------------------------------------------------------------------------
// Fallback (R2 fused kernel, verbatim) — used only if ws is too small.
// ---------------------------------------------------------------------------
__global__ __launch_bounds__(NT, 1)
void dshw_fused(const float* __restrict__ y,
                const float* __restrict__ alphas,
                const float* __restrict__ betas,
                const float* __restrict__ gammas,
                const float* __restrict__ omegas,
                float* __restrict__ out)
{
    __shared__ double sIc[P1c][NT];
    __shared__ double sWc[P2c][NT];

    const int tid = threadIdx.x;
    const int g   = blockIdx.x * NT + tid;
    const int bb  = g >> 4;
    const int f   = g & 15;

    const float* __restrict__ yb = y + (size_t)bb * NSTEP * NFc + f;

    const double al = 1.0 / (1.0 + exp(-(double)alphas[f]));
    const double be = 1.0 / (1.0 + exp(-(double)betas[f]));
    const double ga = 1.0 / (1.0 + exp(-(double)gammas[f]));
    const double om = 1.0 / (1.0 + exp(-(double)omegas[f]));

    double sum48 = 0.0;
    #pragma unroll
    for (int ph = 0; ph < P1c; ++ph) {
        double v0 = (double)yb[ph * NFc];
        double v1 = (double)yb[(ph + P1c) * NFc];
        sIc[ph][tid] = 0.5 * (v0 + v1);
        sum48 += v0 + v1;
    }
    const double inv_mean48 = 48.0 / sum48;
    #pragma unroll
    for (int ph = 0; ph < P1c; ++ph) sIc[ph][tid] *= inv_mean48;

    double sum168a = 0.0, sum168b = 0.0;
    for (int i = 0; i < P2c; ++i) {
        double v0 = (double)yb[i * NFc];
        double v1 = (double)yb[(i + P2c) * NFc];
        sWc[i][tid] = 0.5 * (v0 + v1);
        sum168a += v0;
        sum168b += v1;
    }
    const double mean336 = (sum168a + sum168b) * (1.0 / 336.0);
    for (int i = 0; i < P2c; ++i) {
        sWc[i][tid] = (sWc[i][tid] / mean336) / sIc[i % P1c][tid];
    }

    double tt = 0.5 * ((sum168a - sum168b) * (1.0 / (168.0 * 168.0)) +
                       ((double)yb[(P2c - 1) * NFc] - (double)yb[0]) * (1.0 / 168.0));
    double ss = mean336 - 168.5 * tt;

    float* __restrict__ yh_o = out + OFF_YH + (size_t)bb * NSTEP * NFc + f;
    float* __restrict__ e_o  = out + OFF_E  + (size_t)bb * NSTEP * NFc + f;

    int i1 = 0, i2 = 0;
    int i1p = 2, i2p = 2;

    double Icv0 = sIc[0][tid], Icv1 = sIc[1][tid];
    double wcv0 = sWc[0][tid], wcv1 = sWc[1][tid];
    double yt0 = (double)yb[0 * NFc], yt1 = (double)yb[1 * NFc];
    double yt2 = (double)yb[2 * NFc], yt3 = (double)yb[3 * NFc];

    #pragma unroll 4
    for (int step = 0; step < NSTEP; ++step) {
        double Icv2 = sIc[i1p][tid];
        double wcv2 = sWc[i2p][tid];
        int    pidx = step + 4; pidx = (pidx < NSTEP) ? pidx : (NSTEP - 1);
        double yt4  = (double)yb[pidx * NFc];

        double iw     = Icv0 * wcv0;
        double spt    = ss + tt;
        double yhat   = spt * iw;
        double inv_iw = 1.0 / iw;
        double u      = yt0 * inv_iw;
        double snew   = al * u + (1.0 - al) * spt;
        double tnew   = be * (snew - ss) + (1.0 - be) * tt;
        double q      = yt0 / snew;
        double icn    = ga * (q * (inv_iw * Icv0)) + (1.0 - ga) * Icv0;
        double wcn    = om * (q * (inv_iw * wcv0)) + (1.0 - om) * wcv0;

        sIc[i1][tid] = icn;
        sWc[i2][tid] = wcn;
        yh_o[step * NFc] = (float)yhat;
        e_o[step * NFc]  = (float)(yt0 - yhat);

        ss = snew; tt = tnew;
        Icv0 = Icv1; Icv1 = Icv2;
        wcv0 = wcv1; wcv1 = wcv2;
        yt0 = yt1; yt1 = yt2; yt2 = yt3; yt3 = yt4;
        i1  = (i1  + 1 == P1c) ? 0 : i1  + 1;
        i2  = (i2  + 1 == P2c) ? 0 : i2  + 1;
        i1p = (i1p + 1 == P1c) ? 0 : i1p + 1;
        i2p = (i2p + 1 == P2c) ? 0 : i2p + 1;
    }

    float* __restrict__ fc_o = out + OFF_FC + (size_t)bb * MAXH * NFc + f;
    {
        int k1 = 8, k2 = 8;
        for (int k = 0; k < MAXH; ++k) {
            double cb = sIc[k1][tid];
            double cc = sWc[k2][tid];
            double ca = ss + (double)(k + 1) * tt;
            fc_o[k * NFc] = (float)(ca * cb * cc);
            k1 = (k1 + 1 == P1c) ? 0 : k1 + 1;
            k2 = (k2 + 1 == P2c) ? 0 : k2 + 1;
        }
    }
    {
        float* __restrict__ ic_o = out + OFF_IC + (size_t)bb * P1c * NFc + f;
        int k1 = 8;
        #pragma unroll
        for (int j = 0; j < P1c; ++j) {
            ic_o[j * NFc] = (float)sIc[k1][tid];
            k1 = (k1 + 1 == P1c) ? 0 : k1 + 1;
        }
    }
    {
        float* __restrict__ wc_o = out + OFF_WC + (size_t)bb * P2c * NFc + f;
        int k2 = 8;
        for (int j = 0; j < P2c; ++j) {
            wc_o[j * NFc] = (float)sWc[k2][tid];
            k2 = (k2 + 1 == P2c) ? 0 : k2 + 1;
        }
    }

    out[OFF_T + bb * NFc + f] = (float)tt;
    out[OFF_S + bb * NFc + f] = (float)ss;
}

extern "C" void kernel_launch(void* const* d_in, const int* in_sizes, int n_in,
                              void* d_out, int out_size, void* d_ws, size_t ws_size,
                              hipStream_t stream)
{
    const float* y      = (const float*)d_in[0];
    const float* alphas = (const float*)d_in[1];
    const float* betas  = (const float*)d_in[2];
    const float* gammas = (const float*)d_in[3];
    const float* omegas = (const float*)d_in[4];
    float* out = (float*)d_out;

    if (ws_size >= WS_NEED) {
        double* wsst = (double*)d_ws;
        hipLaunchKernelGGL(dshw_scan4, dim3(NSERIES / NT), dim3(NT), 0, stream,
                           y, alphas, betas, gammas, omegas, wsst, out);
        hipLaunchKernelGGL(dshw_epilogue, dim3(33 * BSc), dim3(256), 0, stream,
                           wsst, out);
    } else {
        hipLaunchKernelGGL(dshw_fused, dim3(NSERIES / NT), dim3(NT), 0, stream,
                           y, alphas, betas, gammas, omegas, out);
    }
}